// Round 11
// baseline (901.053 us; speedup 1.0000x reference)
//
#include <hip/hip_runtime.h>
#include <math.h>

// ---------------------------------------------------------------------------
// LSTNet on MI355X — round 10:
//   FPS v8: centroid carried in registers across iterations. Winning lane
//   publishes key+coords (register select) to the combine slots; next
//   centroid comes straight out of the combine — no pts[far] LDS read, no
//   pts[] staging at all. Reduce = round-8 u64 tree + u64 DPP (best measured).
//   Ballot experiment (round 9) reverted. Everything else = round 8/9.
//   11 launches.
// ---------------------------------------------------------------------------

#define B_ 32
#define N_ 2048
#define NPOINT 512
#define NSAMPLE 16
#define NKNN 16
#define NPTS (B_ * NPOINT)   // 16384

// ---- workspace layout (float offsets) ----
#define WS_BQKV     0         // combined qkv bias (256 f)
#define WS_XYZW     872448    // (B,2048) float4 = 262144 floats
#define WS_NEWXYZ   1134592   // (B,512,3)  49152
#define WS_IDX1     1183744   // int (B,512,16) 262144
#define WS_IDXK     1445888   // int (B,512,16) 262144
#define WS_KF       1708032   // region
#define WS_Q        3805184   // region
#define WS_KFF      7999488   // region (2097152 floats)
#define WS_E1       10096640  // region (4194304 floats)
#define WS_FEAT     14290944  // region (8388608 floats)
#define WS_GF       22679552  // gfenc (B,512) uint = 16384
#define WS_TOTAL    22695936
// KFF-region tenants (dead before attn epilogue writes kffb):
#define WS_WFRAG    WS_KFF               // attn bf16 frags (36864 us)
#define WS_NXYZW    (WS_KFF + 32768)     // packed keypoints (65536 f)
// knn partials (dead before GEMM chain):
#define WS_PD1      WS_FEAT              // 2097152 f
#define WS_PI1      (WS_FEAT + 2097152)  // 2097152 i
#define WS_PD2      WS_E1                // 1048576 f
#define WS_PI2      (WS_E1 + 1048576)    // 1048576 i

// ---- ushort offsets (into (unsigned short*)ws) ----
#define UF_E1   40960    // 32768 us   (K=128,N=256)
#define UF_E2   73728    // 131072 us  (K=256,N=512)
#define UF_M1   204800   // 524288 us  (K=1024,N=512)
#define UF_M2   729088   // 131072 us  (K=512,N=256)
#define UF_M3   860160   // 32768 us   (K=256,N=128)
#define UF_SA1  892928   // 2048 us    (K=32 zero-padded from 6, N=64)
#define UF_SA2  894976   // 8192 us    (K=64,N=128)
#define UF_END  903168   // 8192 us    (t_end: K=64,N=128)
#define UF_QKV  911360   // 32768 us   (combined qkv: K=128,N=256 zero-padded)
// bf16 activations:
#define UB_KFB  3416064  // WS_KF*2            : (NPTS,128) kf
#define UB_QKV  7610368  // WS_Q*2             : (NPTS,256) q|k|v|pad
#define UB_KFF  16261120 // (WS_KFF+131072)*2  : (NPTS,128)
#define UB_E1   20193280 // WS_E1*2            : (NPTS,256)
#define UB_M2   24387584 // (WS_E1+2097152)*2  : (NPTS,256)
#define UB_FEAT 28581888 // WS_FEAT*2          : (NPTS,512)
#define UB_M1   36970496 // (WS_FEAT+4194304)*2: (NPTS,512)

typedef __attribute__((ext_vector_type(8))) short bf16x8;
typedef __attribute__((ext_vector_type(8))) unsigned short u16x8;
typedef __attribute__((ext_vector_type(4))) float f32x4;

__device__ __forceinline__ unsigned short f2bf(float f) {
  unsigned u = __float_as_uint(f);
  u += 0x7fff + ((u >> 16) & 1);  // RNE
  return (unsigned short)(u >> 16);
}
__device__ __forceinline__ float bf2f(unsigned short u) {
  return __uint_as_float((unsigned)u << 16);
}
// order-preserving float<->uint for atomicMax
__device__ __forceinline__ unsigned encf(float f) {
  unsigned b = __float_as_uint(f);
  return b ^ (unsigned)(((int)b >> 31) | 0x80000000);
}
__device__ __forceinline__ float decenc(unsigned u) {
  unsigned b = (u & 0x80000000u) ? (u ^ 0x80000000u) : ~u;
  return __uint_as_float(b);
}

#define MFMA16(a, b, c) __builtin_amdgcn_mfma_f32_16x16x32_bf16((a), (b), (c), 0, 0, 0)
#define LDS_FENCE() __asm__ volatile("" ::: "memory")

// ---------------------------------------------------------------------------
// DPP full-wave max reduction on a u64 key; result valid in lane 63.
// (HW-verified rounds 5-8.)
// ---------------------------------------------------------------------------
__device__ __forceinline__ unsigned long long wave_max_u64(unsigned long long key) {
#define DPP_STEP(ctrl) {                                                      \
    int lo = (int)(unsigned)key;                                              \
    int hi = (int)(unsigned)(key >> 32);                                      \
    int plo = __builtin_amdgcn_update_dpp(lo, lo, ctrl, 0xf, 0xf, false);     \
    int phi = __builtin_amdgcn_update_dpp(hi, hi, ctrl, 0xf, 0xf, false);     \
    unsigned long long pk = ((unsigned long long)(unsigned)phi << 32) |       \
                            (unsigned)plo;                                    \
    key = pk > key ? pk : key; }
  DPP_STEP(0x111)
  DPP_STEP(0x112)
  DPP_STEP(0x114)
  DPP_STEP(0x118)
  DPP_STEP(0x142)
  DPP_STEP(0x143)
#undef DPP_STEP
  return key;
}

// ---------------------------------------------------------------------------
// B-frag pack helper (16x16x32 layout), W row-major (N,K), B = W^T.
// ---------------------------------------------------------------------------
__device__ __forceinline__ void packw(int u, const float* __restrict__ W, int K,
                                      int N16, unsigned short* __restrict__ dst) {
  int l = u & 63;
  int ntk = u >> 6;
  int nt = ntk & (N16 - 1);
  int kt = ntk / N16;
  int n = nt * 16 + (l & 15);
  int kb = kt * 32 + (l >> 4) * 8;
  const float* s = W + (size_t)n * K + kb;
  unsigned short* d = dst + (size_t)u * 8;
#pragma unroll
  for (int j = 0; j < 8; ++j) d[j] = f2bf(s[j]);
}

// ---------------------------------------------------------------------------
// setup body (unchanged).
// ---------------------------------------------------------------------------
__device__ void setup_body(int f,
    const float* __restrict__ pc,
    const float* __restrict__ w_start, const float* __restrict__ w_q,
    const float* __restrict__ w_k, const float* __restrict__ w_v,
    const float* __restrict__ bst, const float* __restrict__ bq,
    const float* __restrict__ bk, const float* __restrict__ bv,
    const float* __restrict__ w1a, const float* __restrict__ w2a,
    const float* __restrict__ wp2,
    const float* __restrict__ we1, const float* __restrict__ we2,
    const float* __restrict__ wm1, const float* __restrict__ wm2,
    const float* __restrict__ wm3,
    const float* __restrict__ sw1, const float* __restrict__ sw2,
    const float* __restrict__ wend,
    float* __restrict__ ws) {
  if (f < 65536) {  // xyzw
    int b = f >> 11, j = f & 2047;
    const float* base = pc + (size_t)b * 3 * 2048;
    float x = base[j], y = base[2048 + j], z = base[4096 + j];
    *(float4*)(ws + WS_XYZW + (size_t)f * 4) = make_float4(x, y, z, x * x + y * y + z * z);
    return;
  }
  int u = f - 65536;
  unsigned short* ws_us = (unsigned short*)ws;
  unsigned short* wf = (unsigned short*)(ws + WS_WFRAG);
  if (u < 2048)  { packw(u, w1a, 64, 16, wf); return; }
  u -= 2048;
  if (u < 2048)  { packw(u, w2a, 256, 4, wf + 16384); return; }
  u -= 2048;
  if (u < 512)   { packw(u, wp2, 64, 4, wf + 32768); return; }
  u -= 512;
  if (u < 4096)  { packw(u, we1, 128, 16, ws_us + UF_E1); return; }
  u -= 4096;
  if (u < 16384) { packw(u, we2, 256, 32, ws_us + UF_E2); return; }
  u -= 16384;
  if (u < 65536) { packw(u, wm1, 1024, 32, ws_us + UF_M1); return; }
  u -= 65536;
  if (u < 16384) { packw(u, wm2, 512, 16, ws_us + UF_M2); return; }
  u -= 16384;
  if (u < 4096)  { packw(u, wm3, 256, 8, ws_us + UF_M3); return; }
  u -= 4096;
  if (u < 256) {  // sa conv1: K=6 zero-padded to 32, N=64. W1 is (64,6).
    int l = u & 63, nt = (u >> 6) & 3;
    int n = nt * 16 + (l & 15);
    int kb = (l >> 4) * 8;
    unsigned short* d = ws_us + UF_SA1 + (size_t)u * 8;
#pragma unroll
    for (int j = 0; j < 8; ++j) {
      int k = kb + j;
      d[j] = (k < 6) ? f2bf(sw1[n * 6 + k]) : 0;
    }
    return;
  }
  u -= 256;
  if (u < 1024)  { packw(u, sw2, 64, 8, ws_us + UF_SA2); return; }
  u -= 1024;
  if (u < 1024)  { packw(u, wend, 64, 8, ws_us + UF_END); return; }
  u -= 1024;
  if (u < 4096) {  // combined qkv' frags: K=128, N=256 (cols>=192 zero)
    int l = u & 63;
    int ntk = u >> 6;
    int nt = ntk & 15;
    int kt = ntk >> 4;
    int n = nt * 16 + (l & 15);
    int kb = kt * 32 + (l >> 4) * 8;
    unsigned short* d = ws_us + UF_QKV + (size_t)u * 8;
    if (n >= 192) {
#pragma unroll
      for (int j = 0; j < 8; ++j) d[j] = 0;
      return;
    }
    const float* wsel = (n < 64) ? w_q : ((n < 128) ? w_k : w_v);
    int nn = n & 63;
#pragma unroll
    for (int j = 0; j < 8; ++j) {
      int k = kb + j;
      float acc = 0.f;
      for (int c = 0; c < 64; ++c)
        acc += wsel[nn * 64 + c] * w_start[c * 128 + k];
      d[j] = f2bf(acc);
    }
    return;
  }
  u -= 4096;
  if (u < 256) {  // combined qkv bias
    float v = 0.f;
    if (u < 192) {
      const float* wsel = (u < 64) ? w_q : ((u < 128) ? w_k : w_v);
      const float* bsel = (u < 64) ? bq : ((u < 128) ? bk : bv);
      int nn = u & 63;
      float acc = bsel[nn];
      for (int c = 0; c < 64; ++c) acc += wsel[nn * 64 + c] * bst[c];
      v = acc;
    }
    ws[WS_BQKV + u] = v;
    return;
  }
  u -= 256;
  if (u < 16384) { ((unsigned*)(ws + WS_GF))[u] = 0; return; }  // gfenc zero
}

// ---------------------------------------------------------------------------
// FPS v8: 4 waves x 8 pts/lane, register-resident; u64 tree + u64 DPP reduce
// (round-8 machinery); winning lane publishes key+coords; the combine yields
// the next centroid directly in registers — zero pts[] LDS in the loop.
// Tie-break: key low word = 2047-j => max picks smallest j. Selected coords
// accumulate in sel[512] (LDS) and flush once after the loop.
// ---------------------------------------------------------------------------
__device__ void fps_body(int b, int t, const float* __restrict__ pc,
                         float* __restrict__ new_xyz,
                         float4* __restrict__ new_xyzw,
                         float4* __restrict__ sel,
                         unsigned long long* __restrict__ kkey,
                         float4* __restrict__ kcd) {
  const float* pb = pc + (size_t)b * 6144;
  int w = t >> 6, l = t & 63;
  int base = w * 512 + l;  // wave w owns j = w*512 + r*64 + l
  float px[8], py[8], pz[8], md[8];
#pragma unroll
  for (int r = 0; r < 8; ++r) {
    int j = base + r * 64;
    px[r] = pb[j]; py[r] = pb[2048 + j]; pz[r] = pb[4096 + j];
    md[r] = 1e10f;
  }
  float cx = pb[0], cy = pb[2048], cz = pb[4096];  // centroid 0 = point 0
  for (int i = 0; i < 512; ++i) {
    if (t == 0) sel[i] = make_float4(cx, cy, cz, cx * cx + cy * cy + cz * cz);
    unsigned long long kk[8];
#pragma unroll
    for (int r = 0; r < 8; ++r) {
      float dx = px[r] - cx, dy = py[r] - cy, dz = pz[r] - cz;
      float d = dx * dx + dy * dy + dz * dz;
      float m = fminf(md[r], d);
      md[r] = m;
      kk[r] = ((unsigned long long)__float_as_uint(m) << 32)
              | (unsigned)(2047 - (base + r * 64));
    }
#pragma unroll
    for (int s = 4; s > 0; s >>= 1)
#pragma unroll
      for (int r = 0; r < s; ++r) kk[r] = kk[r + s] > kk[r] ? kk[r + s] : kk[r];
    unsigned long long key = wave_max_u64(kk[0]);
    unsigned klo = (unsigned)__builtin_amdgcn_readlane((int)(unsigned)key, 63);
    unsigned khi = (unsigned)__builtin_amdgcn_readlane((int)(unsigned)(key >> 32), 63);
    int jw = 2047 - (int)klo;           // wave-local winner (global j)
    int lstar = jw & 63;
    int rstar = (jw >> 6) & 7;
    if (l == lstar) {
      float sx = px[0], sy = py[0], sz = pz[0];
#pragma unroll
      for (int r = 1; r < 8; ++r) {
        if (rstar == r) { sx = px[r]; sy = py[r]; sz = pz[r]; }
      }
      int slot = (i & 1) * 4 + w;
      kkey[slot] = ((unsigned long long)khi << 32) | klo;
      kcd[slot] = make_float4(sx, sy, sz, 0.f);
    }
    __syncthreads();
    const unsigned long long* kb = kkey + (i & 1) * 4;
    const float4* kc = kcd + (i & 1) * 4;
    unsigned long long k0 = kb[0], k1 = kb[1], k2 = kb[2], k3 = kb[3];
    float4 c0 = kc[0], c1 = kc[1], c2 = kc[2], c3 = kc[3];
    if (k1 > k0) { k0 = k1; c0 = c1; }
    if (k3 > k2) { k2 = k3; c2 = c3; }
    if (k2 > k0) { c0 = c2; }
    cx = c0.x; cy = c0.y; cz = c0.z;
  }
  __syncthreads();
  for (int i = t; i < 512; i += 256) {
    float4 c = sel[i];
    new_xyzw[(size_t)b * 512 + i] = c;
    float* o = new_xyz + (size_t)(b * 512 + i) * 3;
    o[0] = c.x; o[1] = c.y; o[2] = c.z;
  }
}

__global__ __launch_bounds__(256) void fps_setup_kernel(
    const float* __restrict__ pc,
    const float* __restrict__ w_start, const float* __restrict__ w_q,
    const float* __restrict__ w_k, const float* __restrict__ w_v,
    const float* __restrict__ bst, const float* __restrict__ bq,
    const float* __restrict__ bk, const float* __restrict__ bv,
    const float* __restrict__ w1a, const float* __restrict__ w2a,
    const float* __restrict__ wp2,
    const float* __restrict__ we1, const float* __restrict__ we2,
    const float* __restrict__ wm1, const float* __restrict__ wm2,
    const float* __restrict__ wm3,
    const float* __restrict__ sw1, const float* __restrict__ sw2,
    const float* __restrict__ wend,
    float* __restrict__ ws,
    float* __restrict__ new_xyz, float4* __restrict__ new_xyzw) {
  __shared__ __align__(16) float4 sel[512];
  __shared__ unsigned long long kkey[8];
  __shared__ __align__(16) float4 kcd[8];
  if (blockIdx.x < 32) {
    fps_body(blockIdx.x, threadIdx.x, pc, new_xyz, new_xyzw, sel, kkey, kcd);
    return;
  }
  setup_body((blockIdx.x - 32) * 256 + threadIdx.x, pc, w_start, w_q, w_k, w_v,
             bst, bq, bk, bv, w1a, w2a, wp2, we1, we2, wm1, wm2, wm3,
             sw1, sw2, wend, ws);
}

// ---------------------------------------------------------------------------
// Chunked KNN bodies (unchanged).
// ---------------------------------------------------------------------------
template <int CHSZ, int NCH>
__device__ __forceinline__ void knn_chunk_body(int bid, int tid,
                                               const float4* __restrict__ refs_all,
                                               int refs_per_batch,
                                               const float4* __restrict__ query,
                                               float* __restrict__ pd,
                                               int* __restrict__ pi) {
  int qb = bid & 63, ch = bid >> 6;
  int q = qb * 256 + tid;
  int b = q >> 9;
  const float4* refs = refs_all + (size_t)b * refs_per_batch + ch * CHSZ;
  float4 qp = query[q];
  float qq = qp.w;
  float bd[16]; int bi[16];
#pragma unroll
  for (int s = 0; s < 16; ++s) { bd[s] = 3.0e38f; bi[s] = 0; }
  for (int j = 0; j < CHSZ; ++j) {
    float4 r = refs[j];
    float d = (qq - 2.0f * (qp.x * r.x + qp.y * r.y + qp.z * r.z)) + r.w;
    if (d < bd[15]) {
      float nd = d; int ni = ch * CHSZ + j;
#pragma unroll
      for (int s = 0; s < 16; ++s) {
        bool sw = nd < bd[s];
        float ob = bd[s]; int oi = bi[s];
        bd[s] = sw ? nd : ob; bi[s] = sw ? ni : oi;
        nd = sw ? ob : nd; ni = sw ? oi : ni;
      }
    }
  }
  float* pdq = pd + ((size_t)q * NCH + ch) * 16;
  int* piq = pi + ((size_t)q * NCH + ch) * 16;
#pragma unroll
  for (int s = 0; s < 16; ++s) { pdq[s] = bd[s]; piq[s] = bi[s]; }
}

template <int NCH>
__device__ __forceinline__ void knn_merge_body(int bid, int tid,
                                               const float* __restrict__ pd,
                                               const int* __restrict__ pi,
                                               int* __restrict__ idx) {
  int q = bid * 256 + tid;
  const float* d0 = pd + (size_t)q * NCH * 16;
  const int* i0 = pi + (size_t)q * NCH * 16;
  float bd[16]; int bi[16];
#pragma unroll
  for (int s = 0; s < 16; ++s) { bd[s] = d0[s]; bi[s] = i0[s]; }
  for (int c = 1; c < NCH; ++c) {
    const float* dc = d0 + c * 16;
    const int* ic = i0 + c * 16;
    for (int s = 0; s < 16; ++s) {
      float d = dc[s];
      if (d >= bd[15]) break;
      float nd = d; int ni = ic[s];
#pragma unroll
      for (int k = 0; k < 16; ++k) {
        bool sw = nd < bd[k];
        float ob = bd[k]; int oi = bi[k];
        bd[k] = sw ? nd : ob; bi[k] = sw ? ni : oi;
        nd = sw ? ob : nd; ni = sw ? oi : ni;
      }
    }
  }
#pragma unroll
  for (int s = 0; s < 16; ++s) idx[(size_t)q * 16 + s] = bi[s];
}

__global__ __launch_bounds__(256) void knn1_chunk_kernel(const float4* __restrict__ xyzw,
                                                         const float4* __restrict__ nxyzw,
                                                         float* __restrict__ pd,
                                                         int* __restrict__ pi) {
  knn_chunk_body<256, 8>(blockIdx.x, threadIdx.x, xyzw, 2048, nxyzw, pd, pi);
}

__global__ __launch_bounds__(256) void combo1_kernel(const float4* __restrict__ nxyzw,
                                                     const float* __restrict__ pd1,
                                                     const int* __restrict__ pi1,
                                                     int* __restrict__ idx1,
                                                     float* __restrict__ pd2,
                                                     int* __restrict__ pi2) {
  if (blockIdx.x < 256)
    knn_chunk_body<128, 4>(blockIdx.x, threadIdx.x, nxyzw, 512, nxyzw, pd2, pi2);
  else
    knn_merge_body<8>(blockIdx.x - 256, threadIdx.x, pd1, pi1, idx1);
}

// ---------------------------------------------------------------------------
// SA wave-per-point MFMA (unchanged; kf bf16 out).
// ---------------------------------------------------------------------------
__device__ __forceinline__ void sa_body(int bid, int t,
                                        const float4* __restrict__ xyzw,
                                        const float* __restrict__ new_xyz,
                                        const int* __restrict__ idx1,
                                        const unsigned short* __restrict__ sa1f,
                                        const unsigned short* __restrict__ sa2f,
                                        const float* __restrict__ b1g,
                                        const float* __restrict__ b2g,
                                        unsigned short* __restrict__ kfb,
                                        unsigned short* __restrict__ h1buf) {
  int w = t >> 6, l = t & 63, x = l & 15, quad = l >> 4;
  int pt = bid * 4 + w;
  int b = pt >> 9;
  int jn = idx1[(size_t)pt * 16 + x];
  float4 n4 = xyzw[(size_t)b * 2048 + jn];
  float c0 = new_xyz[(size_t)pt * 3 + 0];
  float c1 = new_xyz[(size_t)pt * 3 + 1];
  float c2 = new_xyz[(size_t)pt * 3 + 2];
  const f32x4 zero = {0.f, 0.f, 0.f, 0.f};
  bf16x8 xf;
#pragma unroll
  for (int j = 0; j < 8; ++j) xf[j] = 0;
  if (quad == 0) {
    xf[0] = (short)f2bf(n4.x - c0);
    xf[1] = (short)f2bf(n4.y - c1);
    xf[2] = (short)f2bf(n4.z - c2);
    xf[3] = (short)f2bf(n4.x);
    xf[4] = (short)f2bf(n4.y);
    xf[5] = (short)f2bf(n4.z);
  }
  unsigned short* hb = h1buf + w * 16 * 72;
#pragma unroll
  for (int nt = 0; nt < 4; ++nt) {
    f32x4 h = MFMA16(xf, *(const bf16x8*)(sa1f + (nt * 64 + l) * 8), zero);
    float bb = b1g[nt * 16 + x];
#pragma unroll
    for (int r = 0; r < 4; ++r)
      hb[(quad * 4 + r) * 72 + nt * 16 + x] = f2bf(fmaxf(h[r] + bb, 0.0f));
  }
  LDS_FENCE();
  bf16x8 hA0 = *(const bf16x8*)(hb + x * 72 + quad * 8);
  bf16x8 hA1 = *(const bf16x8*)(hb + x * 72 + 32 + quad * 8);
  f32x4 acc[8];
#pragma unroll
  for (int nt = 0; nt < 8; ++nt)
    acc[nt] = MFMA16(hA0, *(const bf16x8*)(sa2f + (nt * 64 + l) * 8), zero);
#pragma unroll
  for (int nt = 0; nt < 8; ++nt)
    acc[nt] = MFMA16(hA1, *(const bf16x8*)(sa2f + ((8 + nt) * 64 + l) * 8), acc[nt]);
#pragma unroll
  for (int nt = 0; nt < 8; ++nt) {
    float bb = b2g[nt * 16 + x];
    float m = fmaxf(fmaxf(acc[nt][0], acc[nt][1]), fmaxf(acc[nt][2], acc[nt][3])) + bb;
    m = fmaxf(m, __shfl_xor(m, 16));
    m = fmaxf(m, __shfl_xor(m, 32));
    if (quad == 0) kfb[(size_t)pt * 128 + nt * 16 + x] = f2bf(m);
  }
}

__global__ __launch_bounds__(256) void combo2_kernel(const float4* __restrict__ xyzw,
                                                     const float* __restrict__ new_xyz,
                                                     const int* __restrict__ idx1,
                                                     const unsigned short* __restrict__ sa1f,
                                                     const unsigned short* __restrict__ sa2f,
                                                     const float* __restrict__ b1g,
                                                     const float* __restrict__ b2g,
                                                     unsigned short* __restrict__ kfb,
                                                     const float* __restrict__ pd2,
                                                     const int* __restrict__ pi2,
                                                     int* __restrict__ idxk) {
  __shared__ __align__(16) unsigned short h1buf[4 * 16 * 72];
  if (blockIdx.x < 4096)
    sa_body(blockIdx.x, threadIdx.x, xyzw, new_xyz, idx1, sa1f, sa2f, b1g, b2g,
            kfb, h1buf);
  else
    knn_merge_body<4>(blockIdx.x - 4096, threadIdx.x, pd2, pi2, idxk);
}

// ---------------------------------------------------------------------------
// MFMA attention + fused t_end/identity epilogue (unchanged).
// ---------------------------------------------------------------------------
__global__ __launch_bounds__(256) void attn_mfma_kernel(
    const unsigned short* __restrict__ qkv, const unsigned short* __restrict__ kfb,
    const int* __restrict__ idx_knn, const float* __restrict__ new_xyz,
    const unsigned short* __restrict__ wfrag,
    const float* __restrict__ ba1, const float* __restrict__ ba2,
    const float* __restrict__ wp1, const float* __restrict__ bp1,
    const float* __restrict__ bp2,
    const unsigned short* __restrict__ wendf, const float* __restrict__ bend,
    unsigned short* __restrict__ kffb, float* __restrict__ out2) {
  const int t = threadIdx.x;
  const int w = t >> 6, l = t & 63;
  const int x = l & 15, quad = l >> 4;
  const unsigned short* w1f = wfrag;
  const unsigned short* w2f = wfrag + 16384;
  const unsigned short* wpf = wfrag + 32768;

  __shared__ float4 wp14[64];
  __shared__ float bp2s[64], ba2s[64], ba1s[256];
  __shared__ __align__(16) float pebuf[4][16 * 68];
  __shared__ __align__(16) unsigned short a1buf[4][16 * 264];
  __shared__ __align__(16) unsigned short aggs[16 * 72];

  if (t < 64) wp14[t] = make_float4(wp1[t * 3], wp1[t * 3 + 1], wp1[t * 3 + 2], bp1[t]);
  else if (t < 128) bp2s[t - 64] = bp2[t - 64];
  else if (t < 192) ba2s[t - 128] = ba2[t - 128];
  if (t < 256) ba1s[t] = ba1[t];
  __syncthreads();

  float* pew = pebuf[w];
  unsigned short* a1w = a1buf[w];
  const f32x4 zero = {0.f, 0.f, 0.f, 0.f};

  for (int pi = 0; pi < 4; ++pi) {
    int pt = blockIdx.x * 16 + w * 4 + pi;
    int b = pt >> 9;
    int jn = idx_knn[(size_t)pt * 16 + x];
    const float* nb = new_xyz + (size_t)(b * 512 + jn) * 3;
    const float* p0 = new_xyz + (size_t)pt * 3;
    float prx = p0[0] - nb[0], pry = p0[1] - nb[1], prz = p0[2] - nb[2];

    bf16x8 hA0, hA1;
#pragma unroll
    for (int j = 0; j < 8; ++j) {
      float4 cf = wp14[quad * 8 + j];
      hA0[j] = (short)f2bf(fmaxf(cf.w + cf.x * prx + cf.y * pry + cf.z * prz, 0.0f));
      float4 cg = wp14[32 + quad * 8 + j];
      hA1[j] = (short)f2bf(fmaxf(cg.w + cg.x * prx + cg.y * pry + cg.z * prz, 0.0f));
    }
    f32x4 pacc[4];
#pragma unroll
    for (int nt = 0; nt < 4; ++nt) {
      bf16x8 b0 = *(const bf16x8*)(wpf + nt * 512 + l * 8);
      bf16x8 b1 = *(const bf16x8*)(wpf + (4 + nt) * 512 + l * 8);
      f32x4 z = MFMA16(hA0, b0, zero);
      pacc[nt] = MFMA16(hA1, b1, z);
    }
    float pev[4][4];
#pragma unroll
    for (int nt = 0; nt < 4; ++nt) {
      float bb = bp2s[nt * 16 + x];
#pragma unroll
      for (int r = 0; r < 4; ++r) {
        float pe = pacc[nt][r] + bb;
        pev[nt][r] = pe;
        pew[(quad * 4 + r) * 68 + nt * 16 + x] = pe;
      }
    }
    LDS_FENCE();

    const unsigned short* qp = qkv + (size_t)pt * 256;
    const unsigned short* kgp = qkv + (size_t)(b * 512 + jn) * 256 + 64;
    const float* per = pew + x * 68;
    u16x8 qa = *(const u16x8*)(qp + quad * 8);
    u16x8 qb = *(const u16x8*)(qp + 32 + quad * 8);
    u16x8 ka = *(const u16x8*)(kgp + quad * 8);
    u16x8 kb = *(const u16x8*)(kgp + 32 + quad * 8);
    float4 p0a = *(const float4*)(per + quad * 8);
    float4 p0b = *(const float4*)(per + quad * 8 + 4);
    float4 p1a = *(const float4*)(per + 32 + quad * 8);
    float4 p1b = *(const float4*)(per + 32 + quad * 8 + 4);
    float pA[8] = {p0a.x, p0a.y, p0a.z, p0a.w, p0b.x, p0b.y, p0b.z, p0b.w};
    float pB[8] = {p1a.x, p1a.y, p1a.z, p1a.w, p1b.x, p1b.y, p1b.z, p1b.w};
    bf16x8 tA0, tA1;
#pragma unroll
    for (int j = 0; j < 8; ++j) {
      tA0[j] = (short)f2bf(bf2f(qa[j]) - bf2f(ka[j]) + pA[j]);
      tA1[j] = (short)f2bf(bf2f(qb[j]) - bf2f(kb[j]) + pB[j]);
    }

    f32x4 acc1[16];
#pragma unroll
    for (int nt = 0; nt < 16; ++nt) {
      bf16x8 bfr = *(const bf16x8*)(w1f + nt * 512 + l * 8);
      acc1[nt] = MFMA16(tA0, bfr, zero);
    }
#pragma unroll
    for (int nt = 0; nt < 16; ++nt) {
      bf16x8 bfr = *(const bf16x8*)(w1f + (16 + nt) * 512 + l * 8);
      acc1[nt] = MFMA16(tA1, bfr, acc1[nt]);
    }
#pragma unroll
    for (int nt = 0; nt < 16; ++nt) {
      float bb = ba1s[nt * 16 + x];
#pragma unroll
      for (int r = 0; r < 4; ++r) {
        a1w[(quad * 4 + r) * 264 + nt * 16 + x] = f2bf(fmaxf(acc1[nt][r] + bb, 0.0f));
      }
    }
    LDS_FENCE();

    f32x4 acc2[4] = {zero, zero, zero, zero};
#pragma unroll
    for (int kt = 0; kt < 8; ++kt) {
      bf16x8 aF = *(const bf16x8*)(a1w + x * 264 + kt * 32 + quad * 8);
#pragma unroll
      for (int nt = 0; nt < 4; ++nt) {
        bf16x8 bfr = *(const bf16x8*)(w2f + (kt * 4 + nt) * 512 + l * 8);
        acc2[nt] = MFMA16(aF, bfr, acc2[nt]);
      }
    }
    LDS_FENCE();

    float aggv[4];
#pragma unroll
    for (int nt = 0; nt < 4; ++nt) {
      float bb = ba2s[nt * 16 + x];
      float vc = bf2f(qkv[(size_t)pt * 256 + 128 + nt * 16 + x]);
      float lg[4];
#pragma unroll
      for (int r = 0; r < 4; ++r) lg[r] = acc2[nt][r] + bb;
      float m = fmaxf(fmaxf(lg[0], lg[1]), fmaxf(lg[2], lg[3]));
      m = fmaxf(m, __shfl_xor(m, 16));
      m = fmaxf(m, __shfl_xor(m, 32));
      float den = 0.f, num = 0.f;
#pragma unroll
      for (int r = 0; r < 4; ++r) {
        float e = __expf(lg[r] - m);
        den += e;
        num += e * (vc + pev[nt][r]);
      }
      den += __shfl_xor(den, 16); den += __shfl_xor(den, 32);
      num += __shfl_xor(num, 16); num += __shfl_xor(num, 32);
      aggv[nt] = num / den;
    }
    float outv = aggv[0];
    if (quad == 1) outv = aggv[1];
    else if (quad == 2) outv = aggv[2];
    else if (quad == 3) outv = aggv[3];
    aggs[(w * 4 + pi) * 72 + l] = f2bf(outv);
  }
  __syncthreads();

  int pt0 = blockIdx.x * 16;
  bf16x8 aF0 = *(const bf16x8*)(aggs + x * 72 + quad * 8);
  bf16x8 aF1 = *(const bf16x8*)(aggs + x * 72 + 32 + quad * 8);
#pragma unroll
  for (int nt2 = 0; nt2 < 2; ++nt2) {
    int nt = w * 2 + nt2;
    f32x4 acc = MFMA16(aF0, *(const bf16x8*)(wendf + (size_t)(0 * 8 + nt) * 512 + l * 8), zero);
    acc = MFMA16(aF1, *(const bf16x8*)(wendf + (size_t)(1 * 8 + nt) * 512 + l * 8), acc);
    int col = nt * 16 + x;
    float bb = bend[col];
#pragma unroll
    for (int r = 0; r < 4; ++r) {
      int pt = pt0 + quad * 4 + r;
      float val = acc[r] + bb + bf2f(kfb[(size_t)pt * 128 + col]);
      kffb[(size_t)pt * 128 + col] = f2bf(val);
      int b = pt >> 9, n = pt & 511;
      out2[(size_t)b * 65536 + (size_t)col * 512 + n] = val;
    }
  }
}

// ---------------------------------------------------------------------------
// bf16 MFMA GEMM (unchanged from round 8).
// ---------------------------------------------------------------------------
template <int ACT, bool CONCAT, bool GFMAX, bool FINAL>
__global__ __launch_bounds__(256) void gemm_bf16_kernel(
    const unsigned short* __restrict__ A, const unsigned short* __restrict__ Bf,
    const float* __restrict__ bias, unsigned short* __restrict__ C,
    int M, int N, int K, const unsigned* __restrict__ gfenc_in,
    unsigned* __restrict__ gfenc_out,
    const float* __restrict__ w4, const float* __restrict__ b4,
    const float* __restrict__ new_xyz,
    float* __restrict__ out0, float* __restrict__ out1) {
  extern __shared__ __align__(16) char gsm[];
  float* gls = (float*)gsm;                                   // 2*128
  unsigned short* tile = (unsigned short*)(gsm + 1024);       // 128*132 (FINAL)
  float* w4s = (float*)(gsm + 1024 + 128 * 132 * 2);          // 1536 (FINAL)
  float* b4s = w4s + 1536;                                    // 12 (FINAL)
  int t = threadIdx.x;
  int l = t & 63, w = t >> 6;
  int x = l & 15, quad = l >> 4;
  int m0 = blockIdx.x * 128 + (w >> 1) * 64;
  int n0 = blockIdx.y * 128 + (w & 1) * 64;
  int N16 = N >> 4;
  if (FINAL) {
    for (int i = t; i < 1536; i += 256) w4s[i] = w4[i];
    if (t < 12) b4s[t] = b4[t];
  }
  const f32x4 zero = {0.f, 0.f, 0.f, 0.f};
  f32x4 acc[4][4];
#pragma unroll
  for (int i = 0; i < 4; ++i)
#pragma unroll
    for (int j = 0; j < 4; ++j) acc[i][j] = zero;

  for (int k0 = 0; k0 < K; k0 += 32) {
    bf16x8 af[4], bfr[4];
#pragma unroll
    for (int mi = 0; mi < 4; ++mi) {
      int arow = m0 + mi * 16 + x;
      if (CONCAT && k0 >= 512) {
        const unsigned* gp = gfenc_in + (size_t)(arow >> 9) * 512 + (k0 - 512) + quad * 8;
        uint4 u0 = *(const uint4*)gp;
        uint4 u1 = *(const uint4*)(gp + 4);
        bf16x8 tv;
        tv[0] = (short)f2bf(decenc(u0.x)); tv[1] = (short)f2bf(decenc(u0.y));
        tv[2] = (short)f2bf(decenc(u0.z)); tv[3] = (short)f2bf(decenc(u0.w));
        tv[4] = (short)f2bf(decenc(u1.x)); tv[5] = (short)f2bf(decenc(u1.y));
        tv[6] = (short)f2bf(decenc(u1.z)); tv[7] = (short)f2bf(decenc(u1.w));
        af[mi] = tv;
      } else {
        const unsigned short* ap;
        if (CONCAT) ap = A + (size_t)arow * 512 + k0 + quad * 8;
        else ap = A + (size_t)arow * K + k0 + quad * 8;
        af[mi] = *(const bf16x8*)ap;
      }
    }
    int bbase = (k0 >> 5) * N16 + (n0 >> 4);
#pragma unroll
    for (int ni = 0; ni < 4; ++ni)
      bfr[ni] = *(const bf16x8*)(Bf + (size_t)(bbase + ni) * 512 + l * 8);
#pragma unroll
    for (int mi = 0; mi < 4; ++mi)
#pragma unroll
      for (int ni = 0; ni < 4; ++ni) acc[mi][ni] = MFMA16(af[mi], bfr[ni], acc[mi][ni]);
  }
  float colmax[4] = {-3.0e38f, -3.0e38f, -3.0e38f, -3.0e38f};
#pragma unroll
  for (int ni = 0; ni < 4; ++ni) {
    int col = n0 + ni * 16 + x;
    float bb = bias[col];
#pragma unroll
    for (int mi = 0; mi < 4; ++mi) {
      int row = m0 + mi * 16 + quad * 4;
#pragma unroll
      for (int r = 0; r < 4; ++r) {
        float v = acc[mi][ni][r] + bb;
        if (ACT == 1) v = fmaxf(v, 0.0f);
        if (ACT == 2) v = (v >= 0.0f) ? v : 0.2f * v;
        if (GFMAX) colmax[ni] = fmaxf(colmax[ni], v);
        if (FINAL) {
          int lrow = (row + r) - blockIdx.x * 128;
          int lcol = col - blockIdx.y * 128;
          tile[lrow * 132 + lcol] = f2bf(v);
        } else {
          C[(size_t)(row + r) * N + col] = f2bf(v);
        }
      }
    }
  }
  if (GFMAX) {
#pragma unroll
    for (int ni = 0; ni < 4; ++ni) {
      float m = colmax[ni];
      m = fmaxf(m, __shfl_xor(m, 16));
      m = fmaxf(m, __shfl_xor(m, 32));
      if (quad == 0) gls[(w >> 1) * 128 + (w & 1) * 64 + ni * 16 + x] = m;
    }
    __syncthreads();
    if (t < 128) {
      float m = fmaxf(gls[t], gls[128 + t]);
      int bidx = (blockIdx.x * 128) >> 9;
      atomicMax(gfenc_out + (size_t)bidx * 512 + blockIdx.y * 128 + t, encf(m));
    }
  }
  if (FINAL) {
    __syncthreads();
    if (t < 128) {
      int gid = blockIdx.x * 128 + t;
      float facc[12];
#pragma unroll
      for (int o = 0; o < 12; ++o) facc[o] = b4s[o];
      const unsigned short* trow = tile + t * 132;
      for (int k = 0; k < 128; k += 4) {
        float x0 = bf2f(trow[k]), x1 = bf2f(trow[k + 1]);
        float x2 = bf2f(trow[k + 2]), x3 = bf2f(trow[k + 3]);
#pragma unroll
        for (int o = 0; o < 12; ++o) {
          facc[o] += x0 * w4s[o * 128 + k] + x1 * w4s[o * 128 + k + 1] +
                     x2 * w4s[o * 128 + k + 2] + x3 * w4s[o * 128 + k + 3];
        }
      }
      float kx = new_xyz[(size_t)gid * 3 + 0];
      float ky = new_xyz[(size_t)gid * 3 + 1];
      float kz = new_xyz[(size_t)gid * 3 + 2];
      int b = gid >> 9, n = gid & 511;
#pragma unroll
      for (int d = 0; d < 3; ++d) {
        float s = kx * facc[d] + ky * facc[3 + d] + kz * facc[6 + d] + facc[9 + d];
        float kp = (d == 0) ? kx : ((d == 1) ? ky : kz);
        out0[(size_t)b * 3072 + (size_t)d * 1024 + n] = s;
        out0[(size_t)b * 3072 + (size_t)d * 1024 + 512 + n] = kp;
        out1[(size_t)b * 1536 + (size_t)d * 512 + n] = s;
      }
    }
  }
}

// ---------------------------------------------------------------------------
extern "C" void kernel_launch(void* const* d_in, const int* in_sizes, int n_in,
                              void* d_out, int out_size, void* d_ws, size_t ws_size,
                              hipStream_t stream) {
  (void)in_sizes; (void)n_in; (void)out_size; (void)ws_size;
  const float* pc        = (const float*)d_in[0];
  const float* sa_w1     = (const float*)d_in[1];
  const float* sa_b1     = (const float*)d_in[2];
  const float* sa_w2     = (const float*)d_in[3];
  const float* sa_b2     = (const float*)d_in[4];
  const float* t_start_w = (const float*)d_in[5];
  const float* t_start_b = (const float*)d_in[6];
  const float* t_q_w     = (const float*)d_in[7];
  const float* t_q_b     = (const float*)d_in[8];
  const float* t_k_w     = (const float*)d_in[9];
  const float* t_k_b     = (const float*)d_in[10];
  const float* t_v_w     = (const float*)d_in[11];
  const float* t_v_b     = (const float*)d_in[12];
  const float* t_pos_w1  = (const float*)d_in[13];
  const float* t_pos_b1  = (const float*)d_in[14];
  const float* t_pos_w2  = (const float*)d_in[15];
  const float* t_pos_b2  = (const float*)d_in[16];
  const float* t_attn_w1 = (const float*)d_in[17];
  const float* t_attn_b1 = (const float*)d_in[18];
  const float* t_attn_w2 = (const float*)d_in[19];
  const float* t_attn_b2 = (const float*)d_in[20];
  const float* t_end_w   = (const float*)d_in[21];
  const float* t_end_b   = (const float*)d_in[22];
  const float* exp_w1    = (const float*)d_in[23];
  const float* exp_b1    = (const float*)d_in[24];
  const float* exp_w2    = (const float*)d_in[25];
  const float* exp_b2    = (const float*)d_in[26];
  const float* mlp_w1    = (const float*)d_in[27];
  const float* mlp_b1    = (const float*)d_in[28];
  const float* mlp_w2    = (const float*)d_in[29];
  const float* mlp_b2    = (const float*)d_in[30];
  const float* mlp_w3    = (const float*)d_in[31];
  const float* mlp_b3    = (const float*)d_in[32];
  const float* mlp_w4    = (const float*)d_in[33];
  const float* mlp_b4    = (const float*)d_in[34];

  float* ws = (float*)d_ws;
  unsigned short* ws_us = (unsigned short*)d_ws;
  unsigned* gfenc = (unsigned*)(ws + WS_GF);
  float* out = (float*)d_out;
  float* out0 = out;            // coarse (32,3,1024)
  float* out1 = out + 98304;    // sym    (32,3,512)
  float* out2 = out + 147456;   // keyfeatures (32,128,512)

  fps_setup_kernel<<<812, 256, 0, stream>>>(pc, t_start_w, t_q_w, t_k_w, t_v_w,
                                            t_start_b, t_q_b, t_k_b, t_v_b,
                                            t_attn_w1, t_attn_w2, t_pos_w2,
                                            exp_w1, exp_w2, mlp_w1, mlp_w2, mlp_w3,
                                            sa_w1, sa_w2, t_end_w, ws,
                                            ws + WS_NEWXYZ, (float4*)(ws + WS_NXYZW));
  knn1_chunk_kernel<<<512, 256, 0, stream>>>((const float4*)(ws + WS_XYZW),
                                             (const float4*)(ws + WS_NXYZW),
                                             ws + WS_PD1, (int*)(ws + WS_PI1));
  combo1_kernel<<<320, 256, 0, stream>>>((const float4*)(ws + WS_NXYZW),
                                         ws + WS_PD1, (const int*)(ws + WS_PI1),
                                         (int*)(ws + WS_IDX1),
                                         ws + WS_PD2, (int*)(ws + WS_PI2));
  combo2_kernel<<<4160, 256, 0, stream>>>((const float4*)(ws + WS_XYZW), ws + WS_NEWXYZ,
                                          (const int*)(ws + WS_IDX1),
                                          ws_us + UF_SA1, ws_us + UF_SA2,
                                          sa_b1, sa_b2, ws_us + UB_KFB,
                                          ws + WS_PD2, (const int*)(ws + WS_PI2),
                                          (int*)(ws + WS_IDXK));
  gemm_bf16_kernel<0, false, false, false><<<dim3(128, 2), 256, 1024, stream>>>(
      ws_us + UB_KFB, ws_us + UF_QKV, ws + WS_BQKV, ws_us + UB_QKV,
      NPTS, 256, 128, nullptr, nullptr, nullptr, nullptr, nullptr, nullptr, nullptr);
  attn_mfma_kernel<<<1024, 256, 0, stream>>>(ws_us + UB_QKV, ws_us + UB_KFB,
                                             (const int*)(ws + WS_IDXK), ws + WS_NEWXYZ,
                                             (const unsigned short*)(ws + WS_WFRAG),
                                             t_attn_b1, t_attn_b2,
                                             t_pos_w1, t_pos_b1, t_pos_b2,
                                             ws_us + UF_END, t_end_b,
                                             ws_us + UB_KFF, out2);
  gemm_bf16_kernel<1, false, false, false><<<dim3(128, 2), 256, 1024, stream>>>(
      ws_us + UB_KFF, ws_us + UF_E1, exp_b1, ws_us + UB_E1, NPTS, 256, 128,
      nullptr, nullptr, nullptr, nullptr, nullptr, nullptr, nullptr);
  gemm_bf16_kernel<0, false, true, false><<<dim3(128, 4), 256, 1024, stream>>>(
      ws_us + UB_E1, ws_us + UF_E2, exp_b2, ws_us + UB_FEAT, NPTS, 512, 256,
      nullptr, gfenc, nullptr, nullptr, nullptr, nullptr, nullptr);
  gemm_bf16_kernel<2, true, false, false><<<dim3(128, 4), 256, 1024, stream>>>(
      ws_us + UB_FEAT, ws_us + UF_M1, mlp_b1, ws_us + UB_M1, NPTS, 512, 1024,
      gfenc, nullptr, nullptr, nullptr, nullptr, nullptr, nullptr);
  gemm_bf16_kernel<2, false, false, false><<<dim3(128, 2), 256, 1024, stream>>>(
      ws_us + UB_M1, ws_us + UF_M2, mlp_b2, ws_us + UB_M2, NPTS, 256, 512,
      nullptr, nullptr, nullptr, nullptr, nullptr, nullptr, nullptr);
  gemm_bf16_kernel<2, false, false, true><<<dim3(128, 1), 256, 41008, stream>>>(
      ws_us + UB_M2, ws_us + UF_M3, mlp_b3, nullptr, NPTS, 128, 256,
      nullptr, nullptr, mlp_w4, mlp_b4, ws + WS_NEWXYZ, out0, out1);
}

// Round 12
// 754.242 us; speedup vs baseline: 1.1946x; 1.1946x over previous
//
#include <hip/hip_runtime.h>
#include <math.h>

// ---------------------------------------------------------------------------
// LSTNet on MI355X — round 11:
//   (a) FPS reverted to round-8 best (u64 tree + u64 DPP, LDS pts staging,
//       farrec, post-loop flush). Rounds 9/10 experiments regressed.
//   (b) knn regrouped: chunks(knn1+knn2) -> merges(1+2) -> sa.
//   11 launches.
// ---------------------------------------------------------------------------

#define B_ 32
#define N_ 2048
#define NPOINT 512
#define NSAMPLE 16
#define NKNN 16
#define NPTS (B_ * NPOINT)   // 16384

// ---- workspace layout (float offsets) ----
#define WS_BQKV     0         // combined qkv bias (256 f)
#define WS_XYZW     872448    // (B,2048) float4 = 262144 floats
#define WS_NEWXYZ   1134592   // (B,512,3)  49152
#define WS_IDX1     1183744   // int (B,512,16) 262144
#define WS_IDXK     1445888   // int (B,512,16) 262144
#define WS_KF       1708032   // region
#define WS_Q        3805184   // region
#define WS_KFF      7999488   // region (2097152 floats)
#define WS_E1       10096640  // region (4194304 floats)
#define WS_FEAT     14290944  // region (8388608 floats)
#define WS_GF       22679552  // gfenc (B,512) uint = 16384
#define WS_TOTAL    22695936
// KFF-region tenants (dead before attn epilogue writes kffb):
#define WS_WFRAG    WS_KFF               // attn bf16 frags (36864 us)
#define WS_NXYZW    (WS_KFF + 32768)     // packed keypoints (65536 f)
// knn partials (dead before GEMM chain):
#define WS_PD1      WS_FEAT              // 2097152 f
#define WS_PI1      (WS_FEAT + 2097152)  // 2097152 i
#define WS_PD2      WS_E1                // 1048576 f
#define WS_PI2      (WS_E1 + 1048576)    // 1048576 i

// ---- ushort offsets (into (unsigned short*)ws) ----
#define UF_E1   40960    // 32768 us   (K=128,N=256)
#define UF_E2   73728    // 131072 us  (K=256,N=512)
#define UF_M1   204800   // 524288 us  (K=1024,N=512)
#define UF_M2   729088   // 131072 us  (K=512,N=256)
#define UF_M3   860160   // 32768 us   (K=256,N=128)
#define UF_SA1  892928   // 2048 us    (K=32 zero-padded from 6, N=64)
#define UF_SA2  894976   // 8192 us    (K=64,N=128)
#define UF_END  903168   // 8192 us    (t_end: K=64,N=128)
#define UF_QKV  911360   // 32768 us   (combined qkv: K=128,N=256 zero-padded)
// bf16 activations:
#define UB_KFB  3416064  // WS_KF*2            : (NPTS,128) kf
#define UB_QKV  7610368  // WS_Q*2             : (NPTS,256) q|k|v|pad
#define UB_KFF  16261120 // (WS_KFF+131072)*2  : (NPTS,128)
#define UB_E1   20193280 // WS_E1*2            : (NPTS,256)
#define UB_M2   24387584 // (WS_E1+2097152)*2  : (NPTS,256)
#define UB_FEAT 28581888 // WS_FEAT*2          : (NPTS,512)
#define UB_M1   36970496 // (WS_FEAT+4194304)*2: (NPTS,512)

typedef __attribute__((ext_vector_type(8))) short bf16x8;
typedef __attribute__((ext_vector_type(8))) unsigned short u16x8;
typedef __attribute__((ext_vector_type(4))) float f32x4;

__device__ __forceinline__ unsigned short f2bf(float f) {
  unsigned u = __float_as_uint(f);
  u += 0x7fff + ((u >> 16) & 1);  // RNE
  return (unsigned short)(u >> 16);
}
__device__ __forceinline__ float bf2f(unsigned short u) {
  return __uint_as_float((unsigned)u << 16);
}
// order-preserving float<->uint for atomicMax
__device__ __forceinline__ unsigned encf(float f) {
  unsigned b = __float_as_uint(f);
  return b ^ (unsigned)(((int)b >> 31) | 0x80000000);
}
__device__ __forceinline__ float decenc(unsigned u) {
  unsigned b = (u & 0x80000000u) ? (u ^ 0x80000000u) : ~u;
  return __uint_as_float(b);
}

#define MFMA16(a, b, c) __builtin_amdgcn_mfma_f32_16x16x32_bf16((a), (b), (c), 0, 0, 0)
#define LDS_FENCE() __asm__ volatile("" ::: "memory")

// ---------------------------------------------------------------------------
// DPP full-wave max reduction on a u64 key; result valid in lane 63.
// ---------------------------------------------------------------------------
__device__ __forceinline__ unsigned long long wave_max_u64(unsigned long long key) {
#define DPP_STEP(ctrl) {                                                      \
    int lo = (int)(unsigned)key;                                              \
    int hi = (int)(unsigned)(key >> 32);                                      \
    int plo = __builtin_amdgcn_update_dpp(lo, lo, ctrl, 0xf, 0xf, false);     \
    int phi = __builtin_amdgcn_update_dpp(hi, hi, ctrl, 0xf, 0xf, false);     \
    unsigned long long pk = ((unsigned long long)(unsigned)phi << 32) |       \
                            (unsigned)plo;                                    \
    key = pk > key ? pk : key; }
  DPP_STEP(0x111)
  DPP_STEP(0x112)
  DPP_STEP(0x114)
  DPP_STEP(0x118)
  DPP_STEP(0x142)
  DPP_STEP(0x143)
#undef DPP_STEP
  return key;
}

// ---------------------------------------------------------------------------
// B-frag pack helper (16x16x32 layout), W row-major (N,K), B = W^T.
// ---------------------------------------------------------------------------
__device__ __forceinline__ void packw(int u, const float* __restrict__ W, int K,
                                      int N16, unsigned short* __restrict__ dst) {
  int l = u & 63;
  int ntk = u >> 6;
  int nt = ntk & (N16 - 1);
  int kt = ntk / N16;
  int n = nt * 16 + (l & 15);
  int kb = kt * 32 + (l >> 4) * 8;
  const float* s = W + (size_t)n * K + kb;
  unsigned short* d = dst + (size_t)u * 8;
#pragma unroll
  for (int j = 0; j < 8; ++j) d[j] = f2bf(s[j]);
}

// ---------------------------------------------------------------------------
// setup body (unchanged).
// ---------------------------------------------------------------------------
__device__ void setup_body(int f,
    const float* __restrict__ pc,
    const float* __restrict__ w_start, const float* __restrict__ w_q,
    const float* __restrict__ w_k, const float* __restrict__ w_v,
    const float* __restrict__ bst, const float* __restrict__ bq,
    const float* __restrict__ bk, const float* __restrict__ bv,
    const float* __restrict__ w1a, const float* __restrict__ w2a,
    const float* __restrict__ wp2,
    const float* __restrict__ we1, const float* __restrict__ we2,
    const float* __restrict__ wm1, const float* __restrict__ wm2,
    const float* __restrict__ wm3,
    const float* __restrict__ sw1, const float* __restrict__ sw2,
    const float* __restrict__ wend,
    float* __restrict__ ws) {
  if (f < 65536) {  // xyzw
    int b = f >> 11, j = f & 2047;
    const float* base = pc + (size_t)b * 3 * 2048;
    float x = base[j], y = base[2048 + j], z = base[4096 + j];
    *(float4*)(ws + WS_XYZW + (size_t)f * 4) = make_float4(x, y, z, x * x + y * y + z * z);
    return;
  }
  int u = f - 65536;
  unsigned short* ws_us = (unsigned short*)ws;
  unsigned short* wf = (unsigned short*)(ws + WS_WFRAG);
  if (u < 2048)  { packw(u, w1a, 64, 16, wf); return; }
  u -= 2048;
  if (u < 2048)  { packw(u, w2a, 256, 4, wf + 16384); return; }
  u -= 2048;
  if (u < 512)   { packw(u, wp2, 64, 4, wf + 32768); return; }
  u -= 512;
  if (u < 4096)  { packw(u, we1, 128, 16, ws_us + UF_E1); return; }
  u -= 4096;
  if (u < 16384) { packw(u, we2, 256, 32, ws_us + UF_E2); return; }
  u -= 16384;
  if (u < 65536) { packw(u, wm1, 1024, 32, ws_us + UF_M1); return; }
  u -= 65536;
  if (u < 16384) { packw(u, wm2, 512, 16, ws_us + UF_M2); return; }
  u -= 16384;
  if (u < 4096)  { packw(u, wm3, 256, 8, ws_us + UF_M3); return; }
  u -= 4096;
  if (u < 256) {  // sa conv1: K=6 zero-padded to 32, N=64. W1 is (64,6).
    int l = u & 63, nt = (u >> 6) & 3;
    int n = nt * 16 + (l & 15);
    int kb = (l >> 4) * 8;
    unsigned short* d = ws_us + UF_SA1 + (size_t)u * 8;
#pragma unroll
    for (int j = 0; j < 8; ++j) {
      int k = kb + j;
      d[j] = (k < 6) ? f2bf(sw1[n * 6 + k]) : 0;
    }
    return;
  }
  u -= 256;
  if (u < 1024)  { packw(u, sw2, 64, 8, ws_us + UF_SA2); return; }
  u -= 1024;
  if (u < 1024)  { packw(u, wend, 64, 8, ws_us + UF_END); return; }
  u -= 1024;
  if (u < 4096) {  // combined qkv' frags: K=128, N=256 (cols>=192 zero)
    int l = u & 63;
    int ntk = u >> 6;
    int nt = ntk & 15;
    int kt = ntk >> 4;
    int n = nt * 16 + (l & 15);
    int kb = kt * 32 + (l >> 4) * 8;
    unsigned short* d = ws_us + UF_QKV + (size_t)u * 8;
    if (n >= 192) {
#pragma unroll
      for (int j = 0; j < 8; ++j) d[j] = 0;
      return;
    }
    const float* wsel = (n < 64) ? w_q : ((n < 128) ? w_k : w_v);
    int nn = n & 63;
#pragma unroll
    for (int j = 0; j < 8; ++j) {
      int k = kb + j;
      float acc = 0.f;
      for (int c = 0; c < 64; ++c)
        acc += wsel[nn * 64 + c] * w_start[c * 128 + k];
      d[j] = f2bf(acc);
    }
    return;
  }
  u -= 4096;
  if (u < 256) {  // combined qkv bias
    float v = 0.f;
    if (u < 192) {
      const float* wsel = (u < 64) ? w_q : ((u < 128) ? w_k : w_v);
      const float* bsel = (u < 64) ? bq : ((u < 128) ? bk : bv);
      int nn = u & 63;
      float acc = bsel[nn];
      for (int c = 0; c < 64; ++c) acc += wsel[nn * 64 + c] * bst[c];
      v = acc;
    }
    ws[WS_BQKV + u] = v;
    return;
  }
  u -= 256;
  if (u < 16384) { ((unsigned*)(ws + WS_GF))[u] = 0; return; }  // gfenc zero
}

// ---------------------------------------------------------------------------
// FPS (round-8 best, reverted): 4 waves x 8 pts/lane register-resident,
// u64-key tree local argmax, per-wave u64 DPP reduce, 1 barrier/iter
// (double-buffered kbuf), no global ops in-loop (farrec + post-loop flush).
// ---------------------------------------------------------------------------
__device__ void fps_body(int b, int t, const float* __restrict__ pc,
                         float* __restrict__ new_xyz,
                         float4* __restrict__ new_xyzw,
                         float4* __restrict__ pts,
                         unsigned long long* __restrict__ kbuf,
                         int* __restrict__ farrec) {
  const float* pb = pc + (size_t)b * 6144;
#pragma unroll
  for (int r = 0; r < 8; ++r) {
    int j = t + r * 256;
    float x = pb[j], y = pb[2048 + j], z = pb[4096 + j];
    pts[j] = make_float4(x, y, z, x * x + y * y + z * z);
  }
  __syncthreads();
  int w = t >> 6, l = t & 63;
  int base = w * 512 + l;
  float px[8], py[8], pz[8], md[8];
#pragma unroll
  for (int r = 0; r < 8; ++r) {
    float4 p = pts[base + r * 64];
    px[r] = p.x; py[r] = p.y; pz[r] = p.z;
    md[r] = 1e10f;
  }
  int far = 0;
  for (int i = 0; i < 512; ++i) {
    float4 cpt = pts[far];
    if (t == 0) farrec[i] = far;
    unsigned long long kk[8];
#pragma unroll
    for (int r = 0; r < 8; ++r) {
      float dx = px[r] - cpt.x, dy = py[r] - cpt.y, dz = pz[r] - cpt.z;
      float d = dx * dx + dy * dy + dz * dz;
      float m = fminf(md[r], d);
      md[r] = m;
      kk[r] = ((unsigned long long)__float_as_uint(m) << 32)
              | (unsigned)(2047 - (base + r * 64));
    }
#pragma unroll
    for (int s = 4; s > 0; s >>= 1)
#pragma unroll
      for (int r = 0; r < s; ++r) kk[r] = kk[r + s] > kk[r] ? kk[r + s] : kk[r];
    unsigned long long key = wave_max_u64(kk[0]);
    if (l == 63) kbuf[(i & 1) * 4 + w] = key;
    __syncthreads();
    const unsigned long long* kb = kbuf + (i & 1) * 4;
    unsigned long long k0 = kb[0], k1 = kb[1], k2 = kb[2], k3 = kb[3];
    k0 = k1 > k0 ? k1 : k0;
    k2 = k3 > k2 ? k3 : k2;
    k0 = k2 > k0 ? k2 : k0;
    far = 2047 - (int)(unsigned)(k0 & 0xffffffffull);
  }
  __syncthreads();
  for (int i = t; i < 512; i += 256) {
    float4 c = pts[farrec[i]];
    new_xyzw[(size_t)b * 512 + i] = c;
    float* o = new_xyz + (size_t)(b * 512 + i) * 3;
    o[0] = c.x; o[1] = c.y; o[2] = c.z;
  }
}

__global__ __launch_bounds__(256) void fps_setup_kernel(
    const float* __restrict__ pc,
    const float* __restrict__ w_start, const float* __restrict__ w_q,
    const float* __restrict__ w_k, const float* __restrict__ w_v,
    const float* __restrict__ bst, const float* __restrict__ bq,
    const float* __restrict__ bk, const float* __restrict__ bv,
    const float* __restrict__ w1a, const float* __restrict__ w2a,
    const float* __restrict__ wp2,
    const float* __restrict__ we1, const float* __restrict__ we2,
    const float* __restrict__ wm1, const float* __restrict__ wm2,
    const float* __restrict__ wm3,
    const float* __restrict__ sw1, const float* __restrict__ sw2,
    const float* __restrict__ wend,
    float* __restrict__ ws,
    float* __restrict__ new_xyz, float4* __restrict__ new_xyzw) {
  __shared__ __align__(16) float4 pts[2048];
  __shared__ unsigned long long kbuf[8];
  __shared__ int farrec[512];
  if (blockIdx.x < 32) {
    fps_body(blockIdx.x, threadIdx.x, pc, new_xyz, new_xyzw, pts, kbuf, farrec);
    return;
  }
  setup_body((blockIdx.x - 32) * 256 + threadIdx.x, pc, w_start, w_q, w_k, w_v,
             bst, bq, bk, bv, w1a, w2a, wp2, we1, we2, wm1, wm2, wm3,
             sw1, sw2, wend, ws);
}

// ---------------------------------------------------------------------------
// Chunked KNN bodies (unchanged).
// ---------------------------------------------------------------------------
template <int CHSZ, int NCH>
__device__ __forceinline__ void knn_chunk_body(int bid, int tid,
                                               const float4* __restrict__ refs_all,
                                               int refs_per_batch,
                                               const float4* __restrict__ query,
                                               float* __restrict__ pd,
                                               int* __restrict__ pi) {
  int qb = bid & 63, ch = bid >> 6;
  int q = qb * 256 + tid;
  int b = q >> 9;
  const float4* refs = refs_all + (size_t)b * refs_per_batch + ch * CHSZ;
  float4 qp = query[q];
  float qq = qp.w;
  float bd[16]; int bi[16];
#pragma unroll
  for (int s = 0; s < 16; ++s) { bd[s] = 3.0e38f; bi[s] = 0; }
  for (int j = 0; j < CHSZ; ++j) {
    float4 r = refs[j];
    float d = (qq - 2.0f * (qp.x * r.x + qp.y * r.y + qp.z * r.z)) + r.w;
    if (d < bd[15]) {
      float nd = d; int ni = ch * CHSZ + j;
#pragma unroll
      for (int s = 0; s < 16; ++s) {
        bool sw = nd < bd[s];
        float ob = bd[s]; int oi = bi[s];
        bd[s] = sw ? nd : ob; bi[s] = sw ? ni : oi;
        nd = sw ? ob : nd; ni = sw ? oi : ni;
      }
    }
  }
  float* pdq = pd + ((size_t)q * NCH + ch) * 16;
  int* piq = pi + ((size_t)q * NCH + ch) * 16;
#pragma unroll
  for (int s = 0; s < 16; ++s) { pdq[s] = bd[s]; piq[s] = bi[s]; }
}

template <int NCH>
__device__ __forceinline__ void knn_merge_body(int bid, int tid,
                                               const float* __restrict__ pd,
                                               const int* __restrict__ pi,
                                               int* __restrict__ idx) {
  int q = bid * 256 + tid;
  const float* d0 = pd + (size_t)q * NCH * 16;
  const int* i0 = pi + (size_t)q * NCH * 16;
  float bd[16]; int bi[16];
#pragma unroll
  for (int s = 0; s < 16; ++s) { bd[s] = d0[s]; bi[s] = i0[s]; }
  for (int c = 1; c < NCH; ++c) {
    const float* dc = d0 + c * 16;
    const int* ic = i0 + c * 16;
    for (int s = 0; s < 16; ++s) {
      float d = dc[s];
      if (d >= bd[15]) break;
      float nd = d; int ni = ic[s];
#pragma unroll
      for (int k = 0; k < 16; ++k) {
        bool sw = nd < bd[k];
        float ob = bd[k]; int oi = bi[k];
        bd[k] = sw ? nd : ob; bi[k] = sw ? ni : oi;
        nd = sw ? ob : nd; ni = sw ? oi : ni;
      }
    }
  }
#pragma unroll
  for (int s = 0; s < 16; ++s) idx[(size_t)q * 16 + s] = bi[s];
}

// chunks: blocks [0,512) = knn1 chunk; [512,768) = knn2 chunk.
__global__ __launch_bounds__(256) void knn_chunks_kernel(const float4* __restrict__ xyzw,
                                                         const float4* __restrict__ nxyzw,
                                                         float* __restrict__ pd1,
                                                         int* __restrict__ pi1,
                                                         float* __restrict__ pd2,
                                                         int* __restrict__ pi2) {
  if (blockIdx.x < 512)
    knn_chunk_body<256, 8>(blockIdx.x, threadIdx.x, xyzw, 2048, nxyzw, pd1, pi1);
  else
    knn_chunk_body<128, 4>(blockIdx.x - 512, threadIdx.x, nxyzw, 512, nxyzw, pd2, pi2);
}

// merges: blocks [0,64) = knn1 merge; [64,128) = knn2 merge.
__global__ __launch_bounds__(256) void knn_merges_kernel(const float* __restrict__ pd1,
                                                         const int* __restrict__ pi1,
                                                         int* __restrict__ idx1,
                                                         const float* __restrict__ pd2,
                                                         const int* __restrict__ pi2,
                                                         int* __restrict__ idxk) {
  if (blockIdx.x < 64)
    knn_merge_body<8>(blockIdx.x, threadIdx.x, pd1, pi1, idx1);
  else
    knn_merge_body<4>(blockIdx.x - 64, threadIdx.x, pd2, pi2, idxk);
}

// ---------------------------------------------------------------------------
// SA wave-per-point MFMA (kf bf16 out).
// ---------------------------------------------------------------------------
__global__ __launch_bounds__(256) void sa_kernel(const float4* __restrict__ xyzw,
                                                 const float* __restrict__ new_xyz,
                                                 const int* __restrict__ idx1,
                                                 const unsigned short* __restrict__ sa1f,
                                                 const unsigned short* __restrict__ sa2f,
                                                 const float* __restrict__ b1g,
                                                 const float* __restrict__ b2g,
                                                 unsigned short* __restrict__ kfb) {
  __shared__ __align__(16) unsigned short h1buf[4 * 16 * 72];
  int t = threadIdx.x;
  int w = t >> 6, l = t & 63, x = l & 15, quad = l >> 4;
  int pt = blockIdx.x * 4 + w;
  int b = pt >> 9;
  int jn = idx1[(size_t)pt * 16 + x];
  float4 n4 = xyzw[(size_t)b * 2048 + jn];
  float c0 = new_xyz[(size_t)pt * 3 + 0];
  float c1 = new_xyz[(size_t)pt * 3 + 1];
  float c2 = new_xyz[(size_t)pt * 3 + 2];
  const f32x4 zero = {0.f, 0.f, 0.f, 0.f};
  bf16x8 xf;
#pragma unroll
  for (int j = 0; j < 8; ++j) xf[j] = 0;
  if (quad == 0) {
    xf[0] = (short)f2bf(n4.x - c0);
    xf[1] = (short)f2bf(n4.y - c1);
    xf[2] = (short)f2bf(n4.z - c2);
    xf[3] = (short)f2bf(n4.x);
    xf[4] = (short)f2bf(n4.y);
    xf[5] = (short)f2bf(n4.z);
  }
  unsigned short* hb = h1buf + w * 16 * 72;
#pragma unroll
  for (int nt = 0; nt < 4; ++nt) {
    f32x4 h = MFMA16(xf, *(const bf16x8*)(sa1f + (nt * 64 + l) * 8), zero);
    float bb = b1g[nt * 16 + x];
#pragma unroll
    for (int r = 0; r < 4; ++r)
      hb[(quad * 4 + r) * 72 + nt * 16 + x] = f2bf(fmaxf(h[r] + bb, 0.0f));
  }
  LDS_FENCE();
  bf16x8 hA0 = *(const bf16x8*)(hb + x * 72 + quad * 8);
  bf16x8 hA1 = *(const bf16x8*)(hb + x * 72 + 32 + quad * 8);
  f32x4 acc[8];
#pragma unroll
  for (int nt = 0; nt < 8; ++nt)
    acc[nt] = MFMA16(hA0, *(const bf16x8*)(sa2f + (nt * 64 + l) * 8), zero);
#pragma unroll
  for (int nt = 0; nt < 8; ++nt)
    acc[nt] = MFMA16(hA1, *(const bf16x8*)(sa2f + ((8 + nt) * 64 + l) * 8), acc[nt]);
#pragma unroll
  for (int nt = 0; nt < 8; ++nt) {
    float bb = b2g[nt * 16 + x];
    float m = fmaxf(fmaxf(acc[nt][0], acc[nt][1]), fmaxf(acc[nt][2], acc[nt][3])) + bb;
    m = fmaxf(m, __shfl_xor(m, 16));
    m = fmaxf(m, __shfl_xor(m, 32));
    if (quad == 0) kfb[(size_t)pt * 128 + nt * 16 + x] = f2bf(m);
  }
}

// ---------------------------------------------------------------------------
// MFMA attention + fused t_end/identity epilogue (unchanged).
// ---------------------------------------------------------------------------
__global__ __launch_bounds__(256) void attn_mfma_kernel(
    const unsigned short* __restrict__ qkv, const unsigned short* __restrict__ kfb,
    const int* __restrict__ idx_knn, const float* __restrict__ new_xyz,
    const unsigned short* __restrict__ wfrag,
    const float* __restrict__ ba1, const float* __restrict__ ba2,
    const float* __restrict__ wp1, const float* __restrict__ bp1,
    const float* __restrict__ bp2,
    const unsigned short* __restrict__ wendf, const float* __restrict__ bend,
    unsigned short* __restrict__ kffb, float* __restrict__ out2) {
  const int t = threadIdx.x;
  const int w = t >> 6, l = t & 63;
  const int x = l & 15, quad = l >> 4;
  const unsigned short* w1f = wfrag;
  const unsigned short* w2f = wfrag + 16384;
  const unsigned short* wpf = wfrag + 32768;

  __shared__ float4 wp14[64];
  __shared__ float bp2s[64], ba2s[64], ba1s[256];
  __shared__ __align__(16) float pebuf[4][16 * 68];
  __shared__ __align__(16) unsigned short a1buf[4][16 * 264];
  __shared__ __align__(16) unsigned short aggs[16 * 72];

  if (t < 64) wp14[t] = make_float4(wp1[t * 3], wp1[t * 3 + 1], wp1[t * 3 + 2], bp1[t]);
  else if (t < 128) bp2s[t - 64] = bp2[t - 64];
  else if (t < 192) ba2s[t - 128] = ba2[t - 128];
  if (t < 256) ba1s[t] = ba1[t];
  __syncthreads();

  float* pew = pebuf[w];
  unsigned short* a1w = a1buf[w];
  const f32x4 zero = {0.f, 0.f, 0.f, 0.f};

  for (int pi = 0; pi < 4; ++pi) {
    int pt = blockIdx.x * 16 + w * 4 + pi;
    int b = pt >> 9;
    int jn = idx_knn[(size_t)pt * 16 + x];
    const float* nb = new_xyz + (size_t)(b * 512 + jn) * 3;
    const float* p0 = new_xyz + (size_t)pt * 3;
    float prx = p0[0] - nb[0], pry = p0[1] - nb[1], prz = p0[2] - nb[2];

    bf16x8 hA0, hA1;
#pragma unroll
    for (int j = 0; j < 8; ++j) {
      float4 cf = wp14[quad * 8 + j];
      hA0[j] = (short)f2bf(fmaxf(cf.w + cf.x * prx + cf.y * pry + cf.z * prz, 0.0f));
      float4 cg = wp14[32 + quad * 8 + j];
      hA1[j] = (short)f2bf(fmaxf(cg.w + cg.x * prx + cg.y * pry + cg.z * prz, 0.0f));
    }
    f32x4 pacc[4];
#pragma unroll
    for (int nt = 0; nt < 4; ++nt) {
      bf16x8 b0 = *(const bf16x8*)(wpf + nt * 512 + l * 8);
      bf16x8 b1 = *(const bf16x8*)(wpf + (4 + nt) * 512 + l * 8);
      f32x4 z = MFMA16(hA0, b0, zero);
      pacc[nt] = MFMA16(hA1, b1, z);
    }
    float pev[4][4];
#pragma unroll
    for (int nt = 0; nt < 4; ++nt) {
      float bb = bp2s[nt * 16 + x];
#pragma unroll
      for (int r = 0; r < 4; ++r) {
        float pe = pacc[nt][r] + bb;
        pev[nt][r] = pe;
        pew[(quad * 4 + r) * 68 + nt * 16 + x] = pe;
      }
    }
    LDS_FENCE();

    const unsigned short* qp = qkv + (size_t)pt * 256;
    const unsigned short* kgp = qkv + (size_t)(b * 512 + jn) * 256 + 64;
    const float* per = pew + x * 68;
    u16x8 qa = *(const u16x8*)(qp + quad * 8);
    u16x8 qb = *(const u16x8*)(qp + 32 + quad * 8);
    u16x8 ka = *(const u16x8*)(kgp + quad * 8);
    u16x8 kb = *(const u16x8*)(kgp + 32 + quad * 8);
    float4 p0a = *(const float4*)(per + quad * 8);
    float4 p0b = *(const float4*)(per + quad * 8 + 4);
    float4 p1a = *(const float4*)(per + 32 + quad * 8);
    float4 p1b = *(const float4*)(per + 32 + quad * 8 + 4);
    float pA[8] = {p0a.x, p0a.y, p0a.z, p0a.w, p0b.x, p0b.y, p0b.z, p0b.w};
    float pB[8] = {p1a.x, p1a.y, p1a.z, p1a.w, p1b.x, p1b.y, p1b.z, p1b.w};
    bf16x8 tA0, tA1;
#pragma unroll
    for (int j = 0; j < 8; ++j) {
      tA0[j] = (short)f2bf(bf2f(qa[j]) - bf2f(ka[j]) + pA[j]);
      tA1[j] = (short)f2bf(bf2f(qb[j]) - bf2f(kb[j]) + pB[j]);
    }

    f32x4 acc1[16];
#pragma unroll
    for (int nt = 0; nt < 16; ++nt) {
      bf16x8 bfr = *(const bf16x8*)(w1f + nt * 512 + l * 8);
      acc1[nt] = MFMA16(tA0, bfr, zero);
    }
#pragma unroll
    for (int nt = 0; nt < 16; ++nt) {
      bf16x8 bfr = *(const bf16x8*)(w1f + (16 + nt) * 512 + l * 8);
      acc1[nt] = MFMA16(tA1, bfr, acc1[nt]);
    }
#pragma unroll
    for (int nt = 0; nt < 16; ++nt) {
      float bb = ba1s[nt * 16 + x];
#pragma unroll
      for (int r = 0; r < 4; ++r) {
        a1w[(quad * 4 + r) * 264 + nt * 16 + x] = f2bf(fmaxf(acc1[nt][r] + bb, 0.0f));
      }
    }
    LDS_FENCE();

    f32x4 acc2[4] = {zero, zero, zero, zero};
#pragma unroll
    for (int kt = 0; kt < 8; ++kt) {
      bf16x8 aF = *(const bf16x8*)(a1w + x * 264 + kt * 32 + quad * 8);
#pragma unroll
      for (int nt = 0; nt < 4; ++nt) {
        bf16x8 bfr = *(const bf16x8*)(w2f + (kt * 4 + nt) * 512 + l * 8);
        acc2[nt] = MFMA16(aF, bfr, acc2[nt]);
      }
    }
    LDS_FENCE();

    float aggv[4];
#pragma unroll
    for (int nt = 0; nt < 4; ++nt) {
      float bb = ba2s[nt * 16 + x];
      float vc = bf2f(qkv[(size_t)pt * 256 + 128 + nt * 16 + x]);
      float lg[4];
#pragma unroll
      for (int r = 0; r < 4; ++r) lg[r] = acc2[nt][r] + bb;
      float m = fmaxf(fmaxf(lg[0], lg[1]), fmaxf(lg[2], lg[3]));
      m = fmaxf(m, __shfl_xor(m, 16));
      m = fmaxf(m, __shfl_xor(m, 32));
      float den = 0.f, num = 0.f;
#pragma unroll
      for (int r = 0; r < 4; ++r) {
        float e = __expf(lg[r] - m);
        den += e;
        num += e * (vc + pev[nt][r]);
      }
      den += __shfl_xor(den, 16); den += __shfl_xor(den, 32);
      num += __shfl_xor(num, 16); num += __shfl_xor(num, 32);
      aggv[nt] = num / den;
    }
    float outv = aggv[0];
    if (quad == 1) outv = aggv[1];
    else if (quad == 2) outv = aggv[2];
    else if (quad == 3) outv = aggv[3];
    aggs[(w * 4 + pi) * 72 + l] = f2bf(outv);
  }
  __syncthreads();

  int pt0 = blockIdx.x * 16;
  bf16x8 aF0 = *(const bf16x8*)(aggs + x * 72 + quad * 8);
  bf16x8 aF1 = *(const bf16x8*)(aggs + x * 72 + 32 + quad * 8);
#pragma unroll
  for (int nt2 = 0; nt2 < 2; ++nt2) {
    int nt = w * 2 + nt2;
    f32x4 acc = MFMA16(aF0, *(const bf16x8*)(wendf + (size_t)(0 * 8 + nt) * 512 + l * 8), zero);
    acc = MFMA16(aF1, *(const bf16x8*)(wendf + (size_t)(1 * 8 + nt) * 512 + l * 8), acc);
    int col = nt * 16 + x;
    float bb = bend[col];
#pragma unroll
    for (int r = 0; r < 4; ++r) {
      int pt = pt0 + quad * 4 + r;
      float val = acc[r] + bb + bf2f(kfb[(size_t)pt * 128 + col]);
      kffb[(size_t)pt * 128 + col] = f2bf(val);
      int b = pt >> 9, n = pt & 511;
      out2[(size_t)b * 65536 + (size_t)col * 512 + n] = val;
    }
  }
}

// ---------------------------------------------------------------------------
// bf16 MFMA GEMM (unchanged from round 8).
// ---------------------------------------------------------------------------
template <int ACT, bool CONCAT, bool GFMAX, bool FINAL>
__global__ __launch_bounds__(256) void gemm_bf16_kernel(
    const unsigned short* __restrict__ A, const unsigned short* __restrict__ Bf,
    const float* __restrict__ bias, unsigned short* __restrict__ C,
    int M, int N, int K, const unsigned* __restrict__ gfenc_in,
    unsigned* __restrict__ gfenc_out,
    const float* __restrict__ w4, const float* __restrict__ b4,
    const float* __restrict__ new_xyz,
    float* __restrict__ out0, float* __restrict__ out1) {
  extern __shared__ __align__(16) char gsm[];
  float* gls = (float*)gsm;                                   // 2*128
  unsigned short* tile = (unsigned short*)(gsm + 1024);       // 128*132 (FINAL)
  float* w4s = (float*)(gsm + 1024 + 128 * 132 * 2);          // 1536 (FINAL)
  float* b4s = w4s + 1536;                                    // 12 (FINAL)
  int t = threadIdx.x;
  int l = t & 63, w = t >> 6;
  int x = l & 15, quad = l >> 4;
  int m0 = blockIdx.x * 128 + (w >> 1) * 64;
  int n0 = blockIdx.y * 128 + (w & 1) * 64;
  int N16 = N >> 4;
  if (FINAL) {
    for (int i = t; i < 1536; i += 256) w4s[i] = w4[i];
    if (t < 12) b4s[t] = b4[t];
  }
  const f32x4 zero = {0.f, 0.f, 0.f, 0.f};
  f32x4 acc[4][4];
#pragma unroll
  for (int i = 0; i < 4; ++i)
#pragma unroll
    for (int j = 0; j < 4; ++j) acc[i][j] = zero;

  for (int k0 = 0; k0 < K; k0 += 32) {
    bf16x8 af[4], bfr[4];
#pragma unroll
    for (int mi = 0; mi < 4; ++mi) {
      int arow = m0 + mi * 16 + x;
      if (CONCAT && k0 >= 512) {
        const unsigned* gp = gfenc_in + (size_t)(arow >> 9) * 512 + (k0 - 512) + quad * 8;
        uint4 u0 = *(const uint4*)gp;
        uint4 u1 = *(const uint4*)(gp + 4);
        bf16x8 tv;
        tv[0] = (short)f2bf(decenc(u0.x)); tv[1] = (short)f2bf(decenc(u0.y));
        tv[2] = (short)f2bf(decenc(u0.z)); tv[3] = (short)f2bf(decenc(u0.w));
        tv[4] = (short)f2bf(decenc(u1.x)); tv[5] = (short)f2bf(decenc(u1.y));
        tv[6] = (short)f2bf(decenc(u1.z)); tv[7] = (short)f2bf(decenc(u1.w));
        af[mi] = tv;
      } else {
        const unsigned short* ap;
        if (CONCAT) ap = A + (size_t)arow * 512 + k0 + quad * 8;
        else ap = A + (size_t)arow * K + k0 + quad * 8;
        af[mi] = *(const bf16x8*)ap;
      }
    }
    int bbase = (k0 >> 5) * N16 + (n0 >> 4);
#pragma unroll
    for (int ni = 0; ni < 4; ++ni)
      bfr[ni] = *(const bf16x8*)(Bf + (size_t)(bbase + ni) * 512 + l * 8);
#pragma unroll
    for (int mi = 0; mi < 4; ++mi)
#pragma unroll
      for (int ni = 0; ni < 4; ++ni) acc[mi][ni] = MFMA16(af[mi], bfr[ni], acc[mi][ni]);
  }
  float colmax[4] = {-3.0e38f, -3.0e38f, -3.0e38f, -3.0e38f};
#pragma unroll
  for (int ni = 0; ni < 4; ++ni) {
    int col = n0 + ni * 16 + x;
    float bb = bias[col];
#pragma unroll
    for (int mi = 0; mi < 4; ++mi) {
      int row = m0 + mi * 16 + quad * 4;
#pragma unroll
      for (int r = 0; r < 4; ++r) {
        float v = acc[mi][ni][r] + bb;
        if (ACT == 1) v = fmaxf(v, 0.0f);
        if (ACT == 2) v = (v >= 0.0f) ? v : 0.2f * v;
        if (GFMAX) colmax[ni] = fmaxf(colmax[ni], v);
        if (FINAL) {
          int lrow = (row + r) - blockIdx.x * 128;
          int lcol = col - blockIdx.y * 128;
          tile[lrow * 132 + lcol] = f2bf(v);
        } else {
          C[(size_t)(row + r) * N + col] = f2bf(v);
        }
      }
    }
  }
  if (GFMAX) {
#pragma unroll
    for (int ni = 0; ni < 4; ++ni) {
      float m = colmax[ni];
      m = fmaxf(m, __shfl_xor(m, 16));
      m = fmaxf(m, __shfl_xor(m, 32));
      if (quad == 0) gls[(w >> 1) * 128 + (w & 1) * 64 + ni * 16 + x] = m;
    }
    __syncthreads();
    if (t < 128) {
      float m = fmaxf(gls[t], gls[128 + t]);
      int bidx = (blockIdx.x * 128) >> 9;
      atomicMax(gfenc_out + (size_t)bidx * 512 + blockIdx.y * 128 + t, encf(m));
    }
  }
  if (FINAL) {
    __syncthreads();
    if (t < 128) {
      int gid = blockIdx.x * 128 + t;
      float facc[12];
#pragma unroll
      for (int o = 0; o < 12; ++o) facc[o] = b4s[o];
      const unsigned short* trow = tile + t * 132;
      for (int k = 0; k < 128; k += 4) {
        float x0 = bf2f(trow[k]), x1 = bf2f(trow[k + 1]);
        float x2 = bf2f(trow[k + 2]), x3 = bf2f(trow[k + 3]);
#pragma unroll
        for (int o = 0; o < 12; ++o) {
          facc[o] += x0 * w4s[o * 128 + k] + x1 * w4s[o * 128 + k + 1] +
                     x2 * w4s[o * 128 + k + 2] + x3 * w4s[o * 128 + k + 3];
        }
      }
      float kx = new_xyz[(size_t)gid * 3 + 0];
      float ky = new_xyz[(size_t)gid * 3 + 1];
      float kz = new_xyz[(size_t)gid * 3 + 2];
      int b = gid >> 9, n = gid & 511;
#pragma unroll
      for (int d = 0; d < 3; ++d) {
        float s = kx * facc[d] + ky * facc[3 + d] + kz * facc[6 + d] + facc[9 + d];
        float kp = (d == 0) ? kx : ((d == 1) ? ky : kz);
        out0[(size_t)b * 3072 + (size_t)d * 1024 + n] = s;
        out0[(size_t)b * 3072 + (size_t)d * 1024 + 512 + n] = kp;
        out1[(size_t)b * 1536 + (size_t)d * 512 + n] = s;
      }
    }
  }
}

// ---------------------------------------------------------------------------
extern "C" void kernel_launch(void* const* d_in, const int* in_sizes, int n_in,
                              void* d_out, int out_size, void* d_ws, size_t ws_size,
                              hipStream_t stream) {
  (void)in_sizes; (void)n_in; (void)out_size; (void)ws_size;
  const float* pc        = (const float*)d_in[0];
  const float* sa_w1     = (const float*)d_in[1];
  const float* sa_b1     = (const float*)d_in[2];
  const float* sa_w2     = (const float*)d_in[3];
  const float* sa_b2     = (const float*)d_in[4];
  const float* t_start_w = (const float*)d_in[5];
  const float* t_start_b = (const float*)d_in[6];
  const float* t_q_w     = (const float*)d_in[7];
  const float* t_q_b     = (const float*)d_in[8];
  const float* t_k_w     = (const float*)d_in[9];
  const float* t_k_b     = (const float*)d_in[10];
  const float* t_v_w     = (const float*)d_in[11];
  const float* t_v_b     = (const float*)d_in[12];
  const float* t_pos_w1  = (const float*)d_in[13];
  const float* t_pos_b1  = (const float*)d_in[14];
  const float* t_pos_w2  = (const float*)d_in[15];
  const float* t_pos_b2  = (const float*)d_in[16];
  const float* t_attn_w1 = (const float*)d_in[17];
  const float* t_attn_b1 = (const float*)d_in[18];
  const float* t_attn_w2 = (const float*)d_in[19];
  const float* t_attn_b2 = (const float*)d_in[20];
  const float* t_end_w   = (const float*)d_in[21];
  const float* t_end_b   = (const float*)d_in[22];
  const float* exp_w1    = (const float*)d_in[23];
  const float* exp_b1    = (const float*)d_in[24];
  const float* exp_w2    = (const float*)d_in[25];
  const float* exp_b2    = (const float*)d_in[26];
  const float* mlp_w1    = (const float*)d_in[27];
  const float* mlp_b1    = (const float*)d_in[28];
  const float* mlp_w2    = (const float*)d_in[29];
  const float* mlp_b2    = (const float*)d_in[30];
  const float* mlp_w3    = (const float*)d_in[31];
  const float* mlp_b3    = (const float*)d_in[32];
  const float* mlp_w4    = (const float*)d_in[33];
  const float* mlp_b4    = (const float*)d_in[34];

  float* ws = (float*)d_ws;
  unsigned short* ws_us = (unsigned short*)d_ws;
  unsigned* gfenc = (unsigned*)(ws + WS_GF);
  float* out = (float*)d_out;
  float* out0 = out;            // coarse (32,3,1024)
  float* out1 = out + 98304;    // sym    (32,3,512)
  float* out2 = out + 147456;   // keyfeatures (32,128,512)

  fps_setup_kernel<<<812, 256, 0, stream>>>(pc, t_start_w, t_q_w, t_k_w, t_v_w,
                                            t_start_b, t_q_b, t_k_b, t_v_b,
                                            t_attn_w1, t_attn_w2, t_pos_w2,
                                            exp_w1, exp_w2, mlp_w1, mlp_w2, mlp_w3,
                                            sa_w1, sa_w2, t_end_w, ws,
                                            ws + WS_NEWXYZ, (float4*)(ws + WS_NXYZW));
  knn_chunks_kernel<<<768, 256, 0, stream>>>((const float4*)(ws + WS_XYZW),
                                             (const float4*)(ws + WS_NXYZW),
                                             ws + WS_PD1, (int*)(ws + WS_PI1),
                                             ws + WS_PD2, (int*)(ws + WS_PI2));
  knn_merges_kernel<<<128, 256, 0, stream>>>(ws + WS_PD1, (const int*)(ws + WS_PI1),
                                             (int*)(ws + WS_IDX1),
                                             ws + WS_PD2, (const int*)(ws + WS_PI2),
                                             (int*)(ws + WS_IDXK));
  sa_kernel<<<4096, 256, 0, stream>>>((const float4*)(ws + WS_XYZW), ws + WS_NEWXYZ,
                                      (const int*)(ws + WS_IDX1),
                                      ws_us + UF_SA1, ws_us + UF_SA2,
                                      sa_b1, sa_b2, ws_us + UB_KFB);
  gemm_bf16_kernel<0, false, false, false><<<dim3(128, 2), 256, 1024, stream>>>(
      ws_us + UB_KFB, ws_us + UF_QKV, ws + WS_BQKV, ws_us + UB_QKV,
      NPTS, 256, 128, nullptr, nullptr, nullptr, nullptr, nullptr, nullptr, nullptr);
  attn_mfma_kernel<<<1024, 256, 0, stream>>>(ws_us + UB_QKV, ws_us + UB_KFB,
                                             (const int*)(ws + WS_IDXK), ws + WS_NEWXYZ,
                                             (const unsigned short*)(ws + WS_WFRAG),
                                             t_attn_b1, t_attn_b2,
                                             t_pos_w1, t_pos_b1, t_pos_b2,
                                             ws_us + UF_END, t_end_b,
                                             ws_us + UB_KFF, out2);
  gemm_bf16_kernel<1, false, false, false><<<dim3(128, 2), 256, 1024, stream>>>(
      ws_us + UB_KFF, ws_us + UF_E1, exp_b1, ws_us + UB_E1, NPTS, 256, 128,
      nullptr, nullptr, nullptr, nullptr, nullptr, nullptr, nullptr);
  gemm_bf16_kernel<0, false, true, false><<<dim3(128, 4), 256, 1024, stream>>>(
      ws_us + UB_E1, ws_us + UF_E2, exp_b2, ws_us + UB_FEAT, NPTS, 512, 256,
      nullptr, gfenc, nullptr, nullptr, nullptr, nullptr, nullptr);
  gemm_bf16_kernel<2, true, false, false><<<dim3(128, 4), 256, 1024, stream>>>(
      ws_us + UB_FEAT, ws_us + UF_M1, mlp_b1, ws_us + UB_M1, NPTS, 512, 1024,
      gfenc, nullptr, nullptr, nullptr, nullptr, nullptr, nullptr);
  gemm_bf16_kernel<2, false, false, false><<<dim3(128, 2), 256, 1024, stream>>>(
      ws_us + UB_M1, ws_us + UF_M2, mlp_b2, ws_us + UB_M2, NPTS, 256, 512,
      nullptr, nullptr, nullptr, nullptr, nullptr, nullptr, nullptr);
  gemm_bf16_kernel<2, false, false, true><<<dim3(128, 1), 256, 41008, stream>>>(
      ws_us + UB_M2, ws_us + UF_M3, mlp_b3, nullptr, NPTS, 128, 256,
      nullptr, nullptr, mlp_w4, mlp_b4, ws + WS_NEWXYZ, out0, out1);
}